// Round 7
// baseline (253.613 us; speedup 1.0000x reference)
//
#include <hip/hip_runtime.h>

// ---------------------------------------------------------------------------
// Attention block: qkv = x@w_in^T+b_in ; flash-attn ; out = ao@w_out^T+b_out
// bf16 MFMA pipeline, fp32 accumulation. MI355X gfx950.
// R7: attn Q-tile doubled to 128 rows (K/V frag reads shared across two
// q-subtiles: 2x MFMA per barrier at same LDS/fetch); gemm2 re-tiled to
// 64x128 blocks (grid 512->1024, latency hiding via TLP). gemm1 unchanged.
// ---------------------------------------------------------------------------

typedef __attribute__((ext_vector_type(8))) __bf16 bf16x8;
typedef __attribute__((ext_vector_type(4))) __bf16 bf16x4;
typedef __attribute__((ext_vector_type(4))) float f32x4;
typedef __attribute__((ext_vector_type(4))) short short4v;

__device__ __forceinline__ f32x4 mfma16(bf16x8 a, bf16x8 b, f32x4 c) {
  return __builtin_amdgcn_mfma_f32_16x16x32_bf16(a, b, c, 0, 0, 0);
}

// PV mfma, K=16: lane holds A[m=lane&15][k=quad*4+j], B[n=lane&15][k=quad*4+j]
#if __has_builtin(__builtin_amdgcn_mfma_f32_16x16x16bf16_1k)
__device__ __forceinline__ f32x4 mfma_pv(bf16x4 a, bf16x4 b, f32x4 c) {
  short4v as = __builtin_bit_cast(short4v, a);
  short4v bs = __builtin_bit_cast(short4v, b);
  return __builtin_amdgcn_mfma_f32_16x16x16bf16_1k(as, bs, c, 0, 0, 0);
}
#else
__device__ __forceinline__ f32x4 mfma_pv(bf16x4 a, bf16x4 b, f32x4 c) {
  __bf16 z = (__bf16)0.f;
  bf16x8 a8 = {a[0], a[1], a[2], a[3], z, z, z, z};
  bf16x8 b8 = {b[0], b[1], b[2], b[3], z, z, z, z};
  return mfma16(a8, b8, c);
}
#endif

__device__ __forceinline__ float fexp2(float x) {
#if __has_builtin(__builtin_amdgcn_exp2f)
  return __builtin_amdgcn_exp2f(x);
#else
  return exp2f(x);
#endif
}

typedef __attribute__((address_space(1))) const unsigned int gu32;
typedef __attribute__((address_space(3))) unsigned int lu32;

// async global->LDS, 16B per lane. LDS dest = wave-uniform base + lane*16.
__device__ __forceinline__ void async16(const void* g, void* l) {
  __builtin_amdgcn_global_load_lds((gu32*)g, (lu32*)l, 16, 0, 0);
}

// ---------------------------------------------------------------------------
// fp32 -> bf16 conversion for all three tensors, one dispatch.
// ---------------------------------------------------------------------------
__global__ __launch_bounds__(256) void cvt_all(const float* __restrict__ x,
                                               __bf16* __restrict__ xb,
                                               const float* __restrict__ wi,
                                               __bf16* __restrict__ wib,
                                               const float* __restrict__ wo,
                                               __bf16* __restrict__ wob) {
  int blk = blockIdx.x;
  const float* in;
  __bf16* out;
  int base;
  if (blk < 4096)      { in = x;  out = xb;  base = 0; }
  else if (blk < 5632) { in = wi; out = wib; base = 4096; }
  else                 { in = wo; out = wob; base = 5632; }
  int i = ((blk - base) * 256 + threadIdx.x) * 8;
  float4 a = *(const float4*)(in + i);
  float4 b = *(const float4*)(in + i + 4);
  bf16x8 o;
  o[0] = (__bf16)a.x; o[1] = (__bf16)a.y; o[2] = (__bf16)a.z; o[3] = (__bf16)a.w;
  o[4] = (__bf16)b.x; o[5] = (__bf16)b.y; o[6] = (__bf16)b.z; o[7] = (__bf16)b.w;
  *(bf16x8*)(out + i) = o;
}

// ---------------------------------------------------------------------------
// NT GEMM, BK=64 single-buffered (R6, unchanged): block 128 x (NB*32),
// 4 waves 2x2, wave tile 64 x (NB*16). WRITE_VT: V-third -> vt transposed.
// ---------------------------------------------------------------------------
template <int NB, bool WRITE_VT, typename OutT>
__global__ __launch_bounds__(256) void gemm_nt(const __bf16* __restrict__ A,
                                               const __bf16* __restrict__ Bm,
                                               const float* __restrict__ bias,
                                               OutT* __restrict__ C, int K, int ldc,
                                               __bf16* __restrict__ vt) {
  __shared__ __bf16 As[128 * 64];
  __shared__ __bf16 Bs[NB * 32 * 64];
  const int t = threadIdx.x;
  const int wv = t >> 6, lane = t & 63;
  const int q16 = lane & 15, quad = lane >> 4;
  const int wm = wv >> 1, wn = wv & 1;
  const long m0 = (long)blockIdx.x * 128;
  const long n0 = (long)blockIdx.y * (NB * 32);

  f32x4 zero = {0.f, 0.f, 0.f, 0.f};
  f32x4 acc[4][NB];
#pragma unroll
  for (int i = 0; i < 4; ++i)
#pragma unroll
    for (int j = 0; j < NB; ++j) acc[i][j] = zero;

  char* AsB = (char*)As;
  char* BsB = (char*)Bs;
  const int sr = t >> 3;
  const int gc = (t & 7) ^ (sr & 7);

  for (int kt = 0; kt < K; kt += 64) {
    __syncthreads();
#pragma unroll
    for (int i = 0; i < 4; ++i)
      async16(A + (m0 + i * 32 + sr) * K + kt + gc * 8, AsB + i * 4096 + wv * 1024);
#pragma unroll
    for (int i = 0; i < NB; ++i)
      async16(Bm + (n0 + i * 32 + sr) * K + kt + gc * 8, BsB + i * 4096 + wv * 1024);
    __syncthreads();

#pragma unroll
    for (int kk = 0; kk < 2; ++kk) {
      bf16x8 af[4], bf[NB];
#pragma unroll
      for (int i = 0; i < 4; ++i) {
        int ra = wm * 64 + i * 16 + q16;
        af[i] = *(const bf16x8*)(AsB + ra * 128 + (((kk * 4 + quad) ^ (ra & 7)) * 16));
      }
#pragma unroll
      for (int j = 0; j < NB; ++j) {
        int rb = wn * (NB * 16) + j * 16 + q16;
        bf[j] = *(const bf16x8*)(BsB + rb * 128 + (((kk * 4 + quad) ^ (rb & 7)) * 16));
      }
#pragma unroll
      for (int i = 0; i < 4; ++i)
#pragma unroll
        for (int j = 0; j < NB; ++j) acc[i][j] = mfma16(af[i], bf[j], acc[i][j]);
    }
  }

  if (WRITE_VT && n0 >= 2048) {
    const int b = (int)(m0 >> 10);
    const int nbase = (int)(m0 - (long)b * 1024) + wm * 64;
#pragma unroll
    for (int j = 0; j < NB; ++j) {
      int col = (int)n0 + wn * (NB * 16) + j * 16 + q16;
      int cc = col - 2048;
      int h = cc >> 6, d = cc & 63;
      float bs = bias[col];
      __bf16* vrow = vt + (((long)(b * 16 + h)) << 16) + (long)d * 1024;
#pragma unroll
      for (int i = 0; i < 4; ++i) {
        int n = nbase + i * 16 + quad * 4;
        bf16x4 o;
#pragma unroll
        for (int r = 0; r < 4; ++r) o[r] = (__bf16)(acc[i][j][r] + bs);
        *(bf16x4*)(vrow + n) = o;
      }
    }
  } else {
#pragma unroll
    for (int j = 0; j < NB; ++j) {
      long col = n0 + wn * (NB * 16) + j * 16 + q16;
      float bs = bias[col];
#pragma unroll
      for (int i = 0; i < 4; ++i) {
        long rowb = m0 + wm * 64 + i * 16 + quad * 4;
#pragma unroll
        for (int r = 0; r < 4; ++r) {
          float v = acc[i][j][r] + bs;
          C[(rowb + r) * (long)ldc + col] = (OutT)v;
        }
      }
    }
  }
}

// ---------------------------------------------------------------------------
// NT GEMM, 64x128 block / BK=64: for the out-projection (M=8192 N=1024).
// Grid (M/64, N/128) = 1024 blocks -> 4/CU for latency hiding.
// 4 waves as 2x2; wave tile 32x64 (2x4 of 16x16). LDS 24 KB.
// ---------------------------------------------------------------------------
template <typename OutT>
__global__ __launch_bounds__(256) void gemm_nt64(const __bf16* __restrict__ A,
                                                 const __bf16* __restrict__ Bm,
                                                 const float* __restrict__ bias,
                                                 OutT* __restrict__ C, int K, int ldc) {
  __shared__ __bf16 As[64 * 64];    // 8 KB
  __shared__ __bf16 Bs[128 * 64];   // 16 KB
  const int t = threadIdx.x;
  const int wv = t >> 6, lane = t & 63;
  const int q16 = lane & 15, quad = lane >> 4;
  const int wm = wv >> 1, wn = wv & 1;
  const long m0 = (long)blockIdx.x * 64;
  const long n0 = (long)blockIdx.y * 128;

  f32x4 zero = {0.f, 0.f, 0.f, 0.f};
  f32x4 acc[2][4];
#pragma unroll
  for (int i = 0; i < 2; ++i)
#pragma unroll
    for (int j = 0; j < 4; ++j) acc[i][j] = zero;

  char* AsB = (char*)As;
  char* BsB = (char*)Bs;
  const int sr = t >> 3;
  const int gc = (t & 7) ^ (sr & 7);

  for (int kt = 0; kt < K; kt += 64) {
    __syncthreads();
#pragma unroll
    for (int i = 0; i < 2; ++i)
      async16(A + (m0 + i * 32 + sr) * K + kt + gc * 8, AsB + i * 4096 + wv * 1024);
#pragma unroll
    for (int i = 0; i < 4; ++i)
      async16(Bm + (n0 + i * 32 + sr) * K + kt + gc * 8, BsB + i * 4096 + wv * 1024);
    __syncthreads();

#pragma unroll
    for (int kk = 0; kk < 2; ++kk) {
      bf16x8 af[2], bf[4];
#pragma unroll
      for (int i = 0; i < 2; ++i) {
        int ra = wm * 32 + i * 16 + q16;
        af[i] = *(const bf16x8*)(AsB + ra * 128 + (((kk * 4 + quad) ^ (ra & 7)) * 16));
      }
#pragma unroll
      for (int j = 0; j < 4; ++j) {
        int rb = wn * 64 + j * 16 + q16;
        bf[j] = *(const bf16x8*)(BsB + rb * 128 + (((kk * 4 + quad) ^ (rb & 7)) * 16));
      }
#pragma unroll
      for (int i = 0; i < 2; ++i)
#pragma unroll
        for (int j = 0; j < 4; ++j) acc[i][j] = mfma16(af[i], bf[j], acc[i][j]);
    }
  }

#pragma unroll
  for (int j = 0; j < 4; ++j) {
    long col = n0 + wn * 64 + j * 16 + q16;
    float bs = bias[col];
#pragma unroll
    for (int i = 0; i < 2; ++i) {
      long rowb = m0 + wm * 32 + i * 16 + quad * 4;
#pragma unroll
      for (int r = 0; r < 4; ++r) {
        float v = acc[i][j][r] + bs;
        C[(rowb + r) * (long)ldc + col] = (OutT)v;
      }
    }
  }
}

// ---------------------------------------------------------------------------
// Flash attention, S^T formulation, no-max softmax (exp2 domain).
// R7: Q-tile 128 rows; 4 waves x 32 q-rows (2 subtiles of 16). K/V staging
// and fragment reads shared across subtiles -> 2x MFMA per barrier.
// qkv bf16 [8192][3072]; vt bf16 [128][64][1024].
// ---------------------------------------------------------------------------
__global__ __launch_bounds__(256) void attn_kernel(const __bf16* __restrict__ qkv,
                                                   const __bf16* __restrict__ vt,
                                                   __bf16* __restrict__ ao) {
  __shared__ __bf16 Ks[64 * 64];  // [kv][d], XOR-swizzled 16B chunks
  __shared__ __bf16 Vt[64 * 64];  // [d][kv], XOR-swizzled 16B chunks
  const int t = threadIdx.x;
  const int wv = t >> 6, lane = t & 63;
  const int q16 = lane & 15, quad = lane >> 4;
  const int bh = blockIdx.x;
  const int b = bh >> 4, h = bh & 15;
  const int q0 = blockIdx.y * 128;
  const long rowbase = (long)b * 1024;

  // Q fragments for 2 subtiles (B-operand), prescale 64^-0.5*log2e
  bf16x8 qf[2][2];
#pragma unroll
  for (int qt = 0; qt < 2; ++qt) {
    long qrow = rowbase + q0 + wv * 32 + qt * 16 + q16;
    const __bf16* qp = qkv + qrow * 3072 + h * 64 + quad * 8;
    qf[qt][0] = *(const bf16x8*)qp;
    qf[qt][1] = *(const bf16x8*)(qp + 32);
#pragma unroll
    for (int j = 0; j < 8; ++j) {
      qf[qt][0][j] = (__bf16)((float)qf[qt][0][j] * 0.18033688f);
      qf[qt][1][j] = (__bf16)((float)qf[qt][1][j] * 0.18033688f);
    }
  }

  f32x4 zero = {0.f, 0.f, 0.f, 0.f};
  f32x4 oacc[2][4];
#pragma unroll
  for (int qt = 0; qt < 2; ++qt)
#pragma unroll
    for (int dt = 0; dt < 4; ++dt) oacc[qt][dt] = zero;
  float lcol[2] = {0.f, 0.f};

  char* KsB = (char*)Ks;
  char* VtB = (char*)Vt;
  const int sr = t >> 3;
  const int sgc = (t & 7) ^ (sr & 7);
  const int sw = q16 & 7;

  for (int kv0 = 0; kv0 < 1024; kv0 += 64) {
    __syncthreads();
    const __bf16* kg = qkv + (rowbase + kv0 + sr) * 3072 + 1024 + h * 64 + sgc * 8;
    async16(kg, KsB + wv * 1024);
    async16(kg + (long)32 * 3072, KsB + 4096 + wv * 1024);
    const __bf16* vg = vt + (long)bh * 65536 + (long)sr * 1024 + kv0 + sgc * 8;
    async16(vg, VtB + wv * 1024);
    async16(vg + (long)32 * 1024, VtB + 4096 + wv * 1024);
    __syncthreads();

    // S^T = K·Q^T : sacc[qt][nt][r] = S[m=q16][kv=nt*16+quad*4+r]
    f32x4 sacc[2][4];
#pragma unroll
    for (int qt = 0; qt < 2; ++qt)
#pragma unroll
      for (int nt = 0; nt < 4; ++nt) sacc[qt][nt] = zero;
#pragma unroll
    for (int nt = 0; nt < 4; ++nt) {
      int kvr = nt * 16 + q16;
      bf16x8 kf0 = *(const bf16x8*)(KsB + kvr * 128 + ((quad ^ sw) * 16));
      bf16x8 kf1 = *(const bf16x8*)(KsB + kvr * 128 + (((4 + quad) ^ sw) * 16));
#pragma unroll
      for (int qt = 0; qt < 2; ++qt) {
        sacc[qt][nt] = mfma16(kf0, qf[qt][0], sacc[qt][nt]);
        sacc[qt][nt] = mfma16(kf1, qf[qt][1], sacc[qt][nt]);
      }
    }

    // p = exp2(s), no max subtraction (bounded inputs)
    bf16x4 pf[2][4];
#pragma unroll
    for (int qt = 0; qt < 2; ++qt)
#pragma unroll
      for (int nt = 0; nt < 4; ++nt)
#pragma unroll
        for (int r = 0; r < 4; ++r) {
          float p = fexp2(sacc[qt][nt][r]);
          lcol[qt] += p;
          pf[qt][nt][r] = (__bf16)p;
        }

    // O += P·V (V-frag reads shared across subtiles)
#pragma unroll
    for (int nt = 0; nt < 4; ++nt) {
      int c = ((nt * 2 + (quad >> 1)) ^ sw) * 16 + (quad & 1) * 8;
#pragma unroll
      for (int dt = 0; dt < 4; ++dt) {
        bf16x4 vf = *(const bf16x4*)(VtB + (dt * 16 + q16) * 128 + c);
#pragma unroll
        for (int qt = 0; qt < 2; ++qt)
          oacc[qt][dt] = mfma_pv(pf[qt][nt], vf, oacc[qt][dt]);
      }
    }
  }

#pragma unroll
  for (int qt = 0; qt < 2; ++qt) {
    float l = lcol[qt];
    l += __shfl_xor(l, 16);
    l += __shfl_xor(l, 32);
    float inv = 1.0f / l;
#pragma unroll
    for (int r = 0; r < 4; ++r) {
      float ir = __shfl(inv, quad * 4 + r);
      long orow = rowbase + q0 + wv * 32 + qt * 16 + quad * 4 + r;
#pragma unroll
      for (int dt = 0; dt < 4; ++dt)
        ao[orow * 1024 + h * 64 + dt * 16 + q16] = (__bf16)(oacc[qt][dt][r] * ir);
    }
  }
}

// ---------------------------------------------------------------------------
// launch
// ---------------------------------------------------------------------------
extern "C" void kernel_launch(void* const* d_in, const int* in_sizes, int n_in,
                              void* d_out, int out_size, void* d_ws, size_t ws_size,
                              hipStream_t stream) {
  const float* x     = (const float*)d_in[0];  // [8192][1024]
  const float* w_in  = (const float*)d_in[1];  // [3072][1024]
  const float* b_in  = (const float*)d_in[2];  // [3072]
  const float* w_out = (const float*)d_in[3];  // [1024][1024]
  const float* b_out = (const float*)d_in[4];  // [1024]
  float* out = (float*)d_out;

  char* ws = (char*)d_ws;
  __bf16* xb   = (__bf16*)(ws);                 // 16 MB
  __bf16* wib  = (__bf16*)(ws + 16777216);      // 6 MB
  __bf16* wob  = (__bf16*)(ws + 23068672);      // 2 MB
  __bf16* qkvb = (__bf16*)(ws + 25165824);      // 48 MB: [8192][3072]
  __bf16* aob  = (__bf16*)(ws + 75497472);      // 16 MB: [8192][1024]
  // vt scratch lives in d_out (32 MB fp32): written by gemm1, read by attn,
  // then fully overwritten by gemm2. 16 MB bf16 [128][64][1024].
  __bf16* vtg  = (__bf16*)d_out;

  cvt_all<<<6144, 256, 0, stream>>>(x, xb, w_in, wib, w_out, wob);
  gemm_nt<4, true, __bf16><<<dim3(64, 24), 256, 0, stream>>>(
      xb, wib, b_in, qkvb, 1024, 3072, vtg);
  attn_kernel<<<dim3(128, 8), 256, 0, stream>>>(qkvb, vtg, aob);
  gemm_nt64<float><<<dim3(128, 8), 256, 0, stream>>>(
      aob, wob, b_out, out, 1024, 1024);
}

// Round 8
// 242.897 us; speedup vs baseline: 1.0441x; 1.0441x over previous
//
#include <hip/hip_runtime.h>

// ---------------------------------------------------------------------------
// Attention block: qkv = x@w_in^T+b_in ; flash-attn ; out = ao@w_out^T+b_out
// bf16 MFMA pipeline, fp32 accumulation. MI355X gfx950.
// R8: attn reverted to R6 (Q64 / VGPR 48 -- R7's Q128 occupancy cliff);
// single experiment: gemm2 = 64x128 tile, 1024 blocks (4/CU) to overlap
// the per-iter barrier drains that 512 blocks (2/CU) left exposed.
// ---------------------------------------------------------------------------

typedef __attribute__((ext_vector_type(8))) __bf16 bf16x8;
typedef __attribute__((ext_vector_type(4))) __bf16 bf16x4;
typedef __attribute__((ext_vector_type(4))) float f32x4;
typedef __attribute__((ext_vector_type(4))) short short4v;

__device__ __forceinline__ f32x4 mfma16(bf16x8 a, bf16x8 b, f32x4 c) {
  return __builtin_amdgcn_mfma_f32_16x16x32_bf16(a, b, c, 0, 0, 0);
}

// PV mfma, K=16: lane holds A[m=lane&15][k=quad*4+j], B[n=lane&15][k=quad*4+j]
#if __has_builtin(__builtin_amdgcn_mfma_f32_16x16x16bf16_1k)
__device__ __forceinline__ f32x4 mfma_pv(bf16x4 a, bf16x4 b, f32x4 c) {
  short4v as = __builtin_bit_cast(short4v, a);
  short4v bs = __builtin_bit_cast(short4v, b);
  return __builtin_amdgcn_mfma_f32_16x16x16bf16_1k(as, bs, c, 0, 0, 0);
}
#else
__device__ __forceinline__ f32x4 mfma_pv(bf16x4 a, bf16x4 b, f32x4 c) {
  __bf16 z = (__bf16)0.f;
  bf16x8 a8 = {a[0], a[1], a[2], a[3], z, z, z, z};
  bf16x8 b8 = {b[0], b[1], b[2], b[3], z, z, z, z};
  return mfma16(a8, b8, c);
}
#endif

__device__ __forceinline__ float fexp2(float x) {
#if __has_builtin(__builtin_amdgcn_exp2f)
  return __builtin_amdgcn_exp2f(x);
#else
  return exp2f(x);
#endif
}

typedef __attribute__((address_space(1))) const unsigned int gu32;
typedef __attribute__((address_space(3))) unsigned int lu32;

// async global->LDS, 16B per lane. LDS dest = wave-uniform base + lane*16.
__device__ __forceinline__ void async16(const void* g, void* l) {
  __builtin_amdgcn_global_load_lds((gu32*)g, (lu32*)l, 16, 0, 0);
}

// ---------------------------------------------------------------------------
// fp32 -> bf16 conversion for all three tensors, one dispatch.
// ---------------------------------------------------------------------------
__global__ __launch_bounds__(256) void cvt_all(const float* __restrict__ x,
                                               __bf16* __restrict__ xb,
                                               const float* __restrict__ wi,
                                               __bf16* __restrict__ wib,
                                               const float* __restrict__ wo,
                                               __bf16* __restrict__ wob) {
  int blk = blockIdx.x;
  const float* in;
  __bf16* out;
  int base;
  if (blk < 4096)      { in = x;  out = xb;  base = 0; }
  else if (blk < 5632) { in = wi; out = wib; base = 4096; }
  else                 { in = wo; out = wob; base = 5632; }
  int i = ((blk - base) * 256 + threadIdx.x) * 8;
  float4 a = *(const float4*)(in + i);
  float4 b = *(const float4*)(in + i + 4);
  bf16x8 o;
  o[0] = (__bf16)a.x; o[1] = (__bf16)a.y; o[2] = (__bf16)a.z; o[3] = (__bf16)a.w;
  o[4] = (__bf16)b.x; o[5] = (__bf16)b.y; o[6] = (__bf16)b.z; o[7] = (__bf16)b.w;
  *(bf16x8*)(out + i) = o;
}

// ---------------------------------------------------------------------------
// NT GEMM, BK=64 single-buffered (R6, unchanged): block 128 x (NB*32),
// 4 waves 2x2, wave tile 64 x (NB*16). WRITE_VT: V-third -> vt transposed.
// ---------------------------------------------------------------------------
template <int NB, bool WRITE_VT, typename OutT>
__global__ __launch_bounds__(256) void gemm_nt(const __bf16* __restrict__ A,
                                               const __bf16* __restrict__ Bm,
                                               const float* __restrict__ bias,
                                               OutT* __restrict__ C, int K, int ldc,
                                               __bf16* __restrict__ vt) {
  __shared__ __bf16 As[128 * 64];
  __shared__ __bf16 Bs[NB * 32 * 64];
  const int t = threadIdx.x;
  const int wv = t >> 6, lane = t & 63;
  const int q16 = lane & 15, quad = lane >> 4;
  const int wm = wv >> 1, wn = wv & 1;
  const long m0 = (long)blockIdx.x * 128;
  const long n0 = (long)blockIdx.y * (NB * 32);

  f32x4 zero = {0.f, 0.f, 0.f, 0.f};
  f32x4 acc[4][NB];
#pragma unroll
  for (int i = 0; i < 4; ++i)
#pragma unroll
    for (int j = 0; j < NB; ++j) acc[i][j] = zero;

  char* AsB = (char*)As;
  char* BsB = (char*)Bs;
  const int sr = t >> 3;
  const int gc = (t & 7) ^ (sr & 7);

  for (int kt = 0; kt < K; kt += 64) {
    __syncthreads();
#pragma unroll
    for (int i = 0; i < 4; ++i)
      async16(A + (m0 + i * 32 + sr) * K + kt + gc * 8, AsB + i * 4096 + wv * 1024);
#pragma unroll
    for (int i = 0; i < NB; ++i)
      async16(Bm + (n0 + i * 32 + sr) * K + kt + gc * 8, BsB + i * 4096 + wv * 1024);
    __syncthreads();

#pragma unroll
    for (int kk = 0; kk < 2; ++kk) {
      bf16x8 af[4], bf[NB];
#pragma unroll
      for (int i = 0; i < 4; ++i) {
        int ra = wm * 64 + i * 16 + q16;
        af[i] = *(const bf16x8*)(AsB + ra * 128 + (((kk * 4 + quad) ^ (ra & 7)) * 16));
      }
#pragma unroll
      for (int j = 0; j < NB; ++j) {
        int rb = wn * (NB * 16) + j * 16 + q16;
        bf[j] = *(const bf16x8*)(BsB + rb * 128 + (((kk * 4 + quad) ^ (rb & 7)) * 16));
      }
#pragma unroll
      for (int i = 0; i < 4; ++i)
#pragma unroll
        for (int j = 0; j < NB; ++j) acc[i][j] = mfma16(af[i], bf[j], acc[i][j]);
    }
  }

  if (WRITE_VT && n0 >= 2048) {
    const int b = (int)(m0 >> 10);
    const int nbase = (int)(m0 - (long)b * 1024) + wm * 64;
#pragma unroll
    for (int j = 0; j < NB; ++j) {
      int col = (int)n0 + wn * (NB * 16) + j * 16 + q16;
      int cc = col - 2048;
      int h = cc >> 6, d = cc & 63;
      float bs = bias[col];
      __bf16* vrow = vt + (((long)(b * 16 + h)) << 16) + (long)d * 1024;
#pragma unroll
      for (int i = 0; i < 4; ++i) {
        int n = nbase + i * 16 + quad * 4;
        bf16x4 o;
#pragma unroll
        for (int r = 0; r < 4; ++r) o[r] = (__bf16)(acc[i][j][r] + bs);
        *(bf16x4*)(vrow + n) = o;
      }
    }
  } else {
#pragma unroll
    for (int j = 0; j < NB; ++j) {
      long col = n0 + wn * (NB * 16) + j * 16 + q16;
      float bs = bias[col];
#pragma unroll
      for (int i = 0; i < 4; ++i) {
        long rowb = m0 + wm * 64 + i * 16 + quad * 4;
#pragma unroll
        for (int r = 0; r < 4; ++r) {
          float v = acc[i][j][r] + bs;
          C[(rowb + r) * (long)ldc + col] = (OutT)v;
        }
      }
    }
  }
}

// ---------------------------------------------------------------------------
// NT GEMM, 64x128 block / BK=64: out-projection (M=8192 N=1024 K=1024).
// Grid (128, 8) = 1024 blocks -> 4/CU; barrier drains overlap across blocks.
// 4 waves as 2x2; wave tile 32x64 (2x4 of 16x16). LDS 24 KB, acc 32 VGPR.
// ---------------------------------------------------------------------------
template <typename OutT>
__global__ __launch_bounds__(256) void gemm_nt64(const __bf16* __restrict__ A,
                                                 const __bf16* __restrict__ Bm,
                                                 const float* __restrict__ bias,
                                                 OutT* __restrict__ C, int K, int ldc) {
  __shared__ __bf16 As[64 * 64];    // 8 KB
  __shared__ __bf16 Bs[128 * 64];   // 16 KB
  const int t = threadIdx.x;
  const int wv = t >> 6, lane = t & 63;
  const int q16 = lane & 15, quad = lane >> 4;
  const int wm = wv >> 1, wn = wv & 1;
  const long m0 = (long)blockIdx.x * 64;
  const long n0 = (long)blockIdx.y * 128;

  f32x4 zero = {0.f, 0.f, 0.f, 0.f};
  f32x4 acc[2][4];
#pragma unroll
  for (int i = 0; i < 2; ++i)
#pragma unroll
    for (int j = 0; j < 4; ++j) acc[i][j] = zero;

  char* AsB = (char*)As;
  char* BsB = (char*)Bs;
  const int sr = t >> 3;
  const int gc = (t & 7) ^ (sr & 7);

  for (int kt = 0; kt < K; kt += 64) {
    __syncthreads();
#pragma unroll
    for (int i = 0; i < 2; ++i)
      async16(A + (m0 + i * 32 + sr) * K + kt + gc * 8, AsB + i * 4096 + wv * 1024);
#pragma unroll
    for (int i = 0; i < 4; ++i)
      async16(Bm + (n0 + i * 32 + sr) * K + kt + gc * 8, BsB + i * 4096 + wv * 1024);
    __syncthreads();

#pragma unroll
    for (int kk = 0; kk < 2; ++kk) {
      bf16x8 af[2], bf[4];
#pragma unroll
      for (int i = 0; i < 2; ++i) {
        int ra = wm * 32 + i * 16 + q16;
        af[i] = *(const bf16x8*)(AsB + ra * 128 + (((kk * 4 + quad) ^ (ra & 7)) * 16));
      }
#pragma unroll
      for (int j = 0; j < 4; ++j) {
        int rb = wn * 64 + j * 16 + q16;
        bf[j] = *(const bf16x8*)(BsB + rb * 128 + (((kk * 4 + quad) ^ (rb & 7)) * 16));
      }
#pragma unroll
      for (int i = 0; i < 2; ++i)
#pragma unroll
        for (int j = 0; j < 4; ++j) acc[i][j] = mfma16(af[i], bf[j], acc[i][j]);
    }
  }

#pragma unroll
  for (int j = 0; j < 4; ++j) {
    long col = n0 + wn * 64 + j * 16 + q16;
    float bs = bias[col];
#pragma unroll
    for (int i = 0; i < 2; ++i) {
      long rowb = m0 + wm * 32 + i * 16 + quad * 4;
#pragma unroll
      for (int r = 0; r < 4; ++r) {
        float v = acc[i][j][r] + bs;
        C[(rowb + r) * (long)ldc + col] = (OutT)v;
      }
    }
  }
}

// ---------------------------------------------------------------------------
// Flash attention, S^T formulation, no-max softmax (exp2 domain). R6 config
// (Q64, VGPR 48 -- best measured).
// qkv bf16 [8192][3072]; vt bf16 [128][64][1024].
// ---------------------------------------------------------------------------
__global__ __launch_bounds__(256) void attn_kernel(const __bf16* __restrict__ qkv,
                                                   const __bf16* __restrict__ vt,
                                                   __bf16* __restrict__ ao) {
  __shared__ __bf16 Ks[64 * 64];  // [kv][d], XOR-swizzled 16B chunks
  __shared__ __bf16 Vt[64 * 64];  // [d][kv], XOR-swizzled 16B chunks
  const int t = threadIdx.x;
  const int wv = t >> 6, lane = t & 63;
  const int q16 = lane & 15, quad = lane >> 4;
  const int bh = blockIdx.x;
  const int b = bh >> 4, h = bh & 15;
  const int q0 = blockIdx.y * 64;
  const long rowbase = (long)b * 1024;

  // Q fragments (B-operand), prescale 64^-0.5 * log2e = 0.18033688
  bf16x8 qf0, qf1;
  {
    long qrow = rowbase + q0 + wv * 16 + q16;
    const __bf16* qp = qkv + qrow * 3072 + h * 64 + quad * 8;
    qf0 = *(const bf16x8*)qp;
    qf1 = *(const bf16x8*)(qp + 32);
#pragma unroll
    for (int j = 0; j < 8; ++j) {
      qf0[j] = (__bf16)((float)qf0[j] * 0.18033688f);
      qf1[j] = (__bf16)((float)qf1[j] * 0.18033688f);
    }
  }

  f32x4 zero = {0.f, 0.f, 0.f, 0.f};
  f32x4 oacc[4];
#pragma unroll
  for (int dt = 0; dt < 4; ++dt) oacc[dt] = zero;
  float lcol = 0.f;

  char* KsB = (char*)Ks;
  char* VtB = (char*)Vt;
  const int sr = t >> 3;
  const int sgc = (t & 7) ^ (sr & 7);
  const int sw = q16 & 7;

  for (int kv0 = 0; kv0 < 1024; kv0 += 64) {
    __syncthreads();
    const __bf16* kg = qkv + (rowbase + kv0 + sr) * 3072 + 1024 + h * 64 + sgc * 8;
    async16(kg, KsB + wv * 1024);
    async16(kg + (long)32 * 3072, KsB + 4096 + wv * 1024);
    const __bf16* vg = vt + (long)bh * 65536 + (long)sr * 1024 + kv0 + sgc * 8;
    async16(vg, VtB + wv * 1024);
    async16(vg + (long)32 * 1024, VtB + 4096 + wv * 1024);
    __syncthreads();

    // S^T = K·Q^T : sacc[nt][r] = S[m=q16][kv=nt*16+quad*4+r]
    f32x4 sacc[4];
#pragma unroll
    for (int nt = 0; nt < 4; ++nt) sacc[nt] = zero;
#pragma unroll
    for (int nt = 0; nt < 4; ++nt) {
      int kvr = nt * 16 + q16;
      bf16x8 kf0 = *(const bf16x8*)(KsB + kvr * 128 + ((quad ^ sw) * 16));
      bf16x8 kf1 = *(const bf16x8*)(KsB + kvr * 128 + (((4 + quad) ^ sw) * 16));
      sacc[nt] = mfma16(kf0, qf0, sacc[nt]);
      sacc[nt] = mfma16(kf1, qf1, sacc[nt]);
    }

    // p = exp2(s), no max subtraction (bounded inputs)
    bf16x4 pf[4];
#pragma unroll
    for (int nt = 0; nt < 4; ++nt)
#pragma unroll
      for (int r = 0; r < 4; ++r) {
        float p = fexp2(sacc[nt][r]);
        lcol += p;
        pf[nt][r] = (__bf16)p;
      }

    // O += P·V
#pragma unroll
    for (int nt = 0; nt < 4; ++nt) {
      int c = ((nt * 2 + (quad >> 1)) ^ sw) * 16 + (quad & 1) * 8;
#pragma unroll
      for (int dt = 0; dt < 4; ++dt) {
        bf16x4 vf = *(const bf16x4*)(VtB + (dt * 16 + q16) * 128 + c);
        oacc[dt] = mfma_pv(pf[nt], vf, oacc[dt]);
      }
    }
  }

  lcol += __shfl_xor(lcol, 16);
  lcol += __shfl_xor(lcol, 32);
  float inv = 1.0f / lcol;
#pragma unroll
  for (int r = 0; r < 4; ++r) {
    float ir = __shfl(inv, quad * 4 + r);
    long orow = rowbase + q0 + wv * 16 + quad * 4 + r;
#pragma unroll
    for (int dt = 0; dt < 4; ++dt)
      ao[orow * 1024 + h * 64 + dt * 16 + q16] = (__bf16)(oacc[dt][r] * ir);
  }
}

// ---------------------------------------------------------------------------
// launch
// ---------------------------------------------------------------------------
extern "C" void kernel_launch(void* const* d_in, const int* in_sizes, int n_in,
                              void* d_out, int out_size, void* d_ws, size_t ws_size,
                              hipStream_t stream) {
  const float* x     = (const float*)d_in[0];  // [8192][1024]
  const float* w_in  = (const float*)d_in[1];  // [3072][1024]
  const float* b_in  = (const float*)d_in[2];  // [3072]
  const float* w_out = (const float*)d_in[3];  // [1024][1024]
  const float* b_out = (const float*)d_in[4];  // [1024]
  float* out = (float*)d_out;

  char* ws = (char*)d_ws;
  __bf16* xb   = (__bf16*)(ws);                 // 16 MB
  __bf16* wib  = (__bf16*)(ws + 16777216);      // 6 MB
  __bf16* wob  = (__bf16*)(ws + 23068672);      // 2 MB
  __bf16* qkvb = (__bf16*)(ws + 25165824);      // 48 MB: [8192][3072]
  __bf16* aob  = (__bf16*)(ws + 75497472);      // 16 MB: [8192][1024]
  // vt scratch lives in d_out (32 MB fp32): written by gemm1, read by attn,
  // then fully overwritten by gemm2. 16 MB bf16 [128][64][1024].
  __bf16* vtg  = (__bf16*)d_out;

  cvt_all<<<6144, 256, 0, stream>>>(x, xb, w_in, wib, w_out, wob);
  gemm_nt<4, true, __bf16><<<dim3(64, 24), 256, 0, stream>>>(
      xb, wib, b_in, qkvb, 1024, 3072, vtg);
  attn_kernel<<<dim3(128, 16), 256, 0, stream>>>(qkvb, vtg, aob);
  gemm_nt64<float><<<dim3(128, 8), 256, 0, stream>>>(
      aob, wob, b_out, out, 1024, 1024);
}